// Round 10
// baseline (252.602 us; speedup 1.0000x reference)
//
#include <hip/hip_runtime.h>

#define SS 1024
#define BB 128
#define HH 1024
#define DD 2048
#define NROWS (SS*BB)            // 131072 (t,b) rows
#define TSEG 64                  // scan segment = 64 timesteps
#define NSEG 16
#define NSCANB 16                // kernel B: scan blocks (1 wave each)
#define NK3B 512                 // kernel B: k3 blocks (4 waves -> 2048 waves)
#define NBLKB (NSCANB + NK3B)    // 528 blocks <= 1024 co-resident @ lb(256,4)
#define L2E  1.4426950408889634f

// scandone flag: flags[4096 + seg*32], target 16
#define SCFLAG(s)    (4096 + (s)*32)
#define FLAG_INTS    4608

typedef float f32x4 __attribute__((ext_vector_type(4)));

__device__ __forceinline__ float fast_rcp(float x)  { return __builtin_amdgcn_rcpf(x); }
__device__ __forceinline__ float exp2_(float x)     { return __builtin_amdgcn_exp2f(x); }

// Write-through stores (sc0 sc1): land at device coherence point, no dirty
// L2 copy (R16 lesson). Used ONLY by the scan (s_out/finals), drained once
// per segment by an explicit vmcnt(0) before the flag add (R17 lesson: no
// compiler load-waits interleave with pending WT ACKs).
__device__ __forceinline__ void st_wt(float* p, float v){
    asm volatile("global_store_dword %0, %1, off sc0 sc1" :: "v"(p), "v"(v));
}
__device__ __forceinline__ void st_wt_x4(float* p, f32x4 v){
    asm volatile("global_store_dwordx4 %0, %1, off sc0 sc1" :: "v"(p), "v"(v));
}

template<int CTRL>
__device__ __forceinline__ float qperm(float x){
    return __int_as_float(__builtin_amdgcn_update_dpp(0, __float_as_int(x), CTRL, 0xF, 0xF, true));
}
__device__ __forceinline__ float rowshr4(float x){
    return __int_as_float(__builtin_amdgcn_update_dpp(0, __float_as_int(x), 0x114, 0xF, 0xF, true));
}

// R21 dispatch A: pure k1 (x -> pre preactivations) + weight sums.
// 2048 blocks x 4 waves, 16 consecutive rows/wave. Plain stores; the
// dispatch boundary release/acquire makes pre visible to kernel B.
__global__ __launch_bounds__(256) void k1_all(
    const float* __restrict__ x, const float* __restrict__ W,
    const float* __restrict__ bias, float* out, float* __restrict__ sums)
{
    float* pre = out + (size_t)NROWS * HH;   // hT/cT rows (2 MB) as pre scratch
    const int tid  = threadIdx.x;
    const int lane = tid & 63;
    const int wv   = tid >> 6;

    if (blockIdx.x == 0 && tid < 64) {
        // 12 weight sums (block 0, wave 0) -> sums workspace
        for (int s = 0; s < 12; ++s) {
            const int base = (s < 4) ? s*DD
                           : (s < 8) ? 4*DD + (s-4)*DD
                                     : 4*DD + (s-8)*DD + HH;
            float v = 0.f;
            #pragma unroll
            for (int k = 0; k < 16; ++k) v += W[base + lane + k*64];
            #pragma unroll
            for (int off = 32; off >= 1; off >>= 1) v += __shfl_xor(v, off, 64);
            if (lane == 0) sums[s] = v;
        }
    }

    const int gw = blockIdx.x*4 + wv;        // 0..8191, 16 rows each
    float4 wvv[4][4];
    #pragma unroll
    for (int j = 0; j < 4; ++j)
        #pragma unroll
        for (int it = 0; it < 4; ++it)
            wvv[j][it] = *(const float4*)(W + j*DD + HH + it*256 + lane*4);
    const float4 b0 = *(const float4*)(bias);

    #pragma unroll 2
    for (int j = 0; j < 16; ++j) {
        const int row = gw*16 + j;
        const float* xr = x + (size_t)row * HH;
        float a0 = 0.f, a1 = 0.f, a2 = 0.f, a3 = 0.f;
        #pragma unroll
        for (int it = 0; it < 4; ++it) {
            f32x4 xv = __builtin_nontemporal_load((const f32x4*)xr + it*64 + lane);
            a0 = fmaf(xv.x, wvv[0][it].x, fmaf(xv.y, wvv[0][it].y, fmaf(xv.z, wvv[0][it].z, fmaf(xv.w, wvv[0][it].w, a0))));
            a1 = fmaf(xv.x, wvv[1][it].x, fmaf(xv.y, wvv[1][it].y, fmaf(xv.z, wvv[1][it].z, fmaf(xv.w, wvv[1][it].w, a1))));
            a2 = fmaf(xv.x, wvv[2][it].x, fmaf(xv.y, wvv[2][it].y, fmaf(xv.z, wvv[2][it].z, fmaf(xv.w, wvv[2][it].w, a2))));
            a3 = fmaf(xv.x, wvv[3][it].x, fmaf(xv.y, wvv[3][it].y, fmaf(xv.z, wvv[3][it].z, fmaf(xv.w, wvv[3][it].w, a3))));
        }
        #pragma unroll
        for (int off = 32; off >= 1; off >>= 1) {
            a0 += __shfl_xor(a0, off, 64);
            a1 += __shfl_xor(a1, off, 64);
            a2 += __shfl_xor(a2, off, 64);
            a3 += __shfl_xor(a3, off, 64);
        }
        if (lane == 0) {
            float4 r = make_float4((a0 + b0.x) * (-L2E),
                                   (a1 + b0.y) * ( 2.0f * L2E),
                                   (a2 + b0.z) * (-L2E),
                                   (a3 + b0.w) * (-L2E));
            const int b = row & (BB-1), t = row >> 7;
            *(float4*)(pre + (((size_t)b << 10) + t) * 4) = r;   // [b][t][gate]
        }
    }
}

// R21 dispatch B: scan || k3. pre fully ready (dispatch boundary), so the
// scan waits on nothing and runs at chain speed, publishing s_out[b][t] per
// 64-step segment via WT stores + vmcnt(0) + flag (R18-proven protocol).
// 2048 k3 waves chase flags (hierarchical LDS poll) and stream the 514 MB
// of out writes. 528 blocks <= 1024 co-resident (VGPR<=128 via lb(256,4))
// -> every block resident, no launch-order assumption.
__global__ __launch_bounds__(256, 4) void scan_k3(
    const float* __restrict__ bias, float* out,
    float* __restrict__ s_out, float* __restrict__ finals,
    const float* __restrict__ sums, int* __restrict__ flags)
{
    __shared__ int ready;
    float* pre = out + (size_t)NROWS * HH;
    const int tid  = threadIdx.x;
    const int lane = tid & 63;
    const int wv   = tid >> 6;
    const int blk  = blockIdx.x;

    if (blk < NSCANB) {
        if (wv != 0) return;                 // 1 scan wave per block
        const int gate = lane & 3;
        const int L    = (lane >> 2) & 1;
        const int lb   = lane >> 3;
        const int bb   = blk*8 + lb;

        const float sh = sums[L*4 + gate];
        const float sx = sums[8 + gate];
        const float sc  = (gate == 1) ? (2.0f*L2E) : (-L2E);
        const float s_h = sh * sc;
        const float sxc = L ? sx * sc : 0.0f;
        const float pcc = L ? bias[4+gate] * sc : 0.0f;
        const float Ac  = (gate == 1) ? 1.0f : 0.0f;
        const float Bc  = (gate == 0) ? (2.0f*L2E) : ((gate == 1) ? -2.0f : 1.0f);

        const float* pbase = pre + ((size_t)bb << 12) + gate;   // + t*4
        float* so = s_out + (size_t)bb * SS;                    // [b][t]

        float h = 0.f, cp = 0.f, h0d1 = 0.f, h0d2 = 0.f;
        float hb0 = 0.f, hb1 = 0.f, hb2 = 0.f, hb3 = 0.f;

        for (int s = 0; s < NSEG; ++s) {
            const int t_lo = s*TSEG, t_hi = t_lo + TSEG;
            float buf[TSEG];
            #pragma unroll
            for (int uu = 0; uu < TSEG; ++uu)
                buf[uu] = pbase[(size_t)(t_lo + uu) * 4];

            #pragma unroll
            for (int uu = 0; uu < TSEG; ++uu) {
                const float p = L ? pcc : buf[uu];
                const float P = fmaf(h0d2, sxc, p);      // L1 consumes h0_{t-2}
                const float g = fmaf(h, s_h, P);
                const float v = fmaf(Bc, fast_rcp(1.0f + exp2_(g)), Ac);
                const float w = v * qperm<0xB1>(v);
                const float cpn = fmaf(qperm<0xAA>(v), cp, qperm<0x00>(w));
                const float th = fmaf(-2.0f, fast_rcp(1.0f + exp2_(cpn)), 1.0f);
                const float hn = qperm<0xFF>(v) * th;
                // first 2 steps: L1 redoes previous segment's flush / spin-up
                const bool disc = (uu < 2) && L;
                h  = disc ? h  : hn;
                cp = disc ? cp : cpn;
                h0d2 = h0d1;
                h0d1 = rowshr4(h);                       // L0 h -> L1 quad (DPP)

                // L1's h at loop-uu is h1[t_lo+uu-2]; slot = (uu+2)&3
                if (((uu+2)&3)==0) hb0 = h;
                else if (((uu+2)&3)==1) hb1 = h;
                else if (((uu+2)&3)==2) hb2 = h;
                else hb3 = h;
                // store 4 rows once slot 3 filled; uu==1 covers prev segment
                if (((uu&3)==1) && uu >= 5 && L && gate == 0) {
                    f32x4 hv = {hb0,hb1,hb2,hb3};
                    st_wt_x4(so + t_lo + uu - 5, hv);
                }
            }

            const float h0f = h, c0f = cp;   // L0 finals (flush skips L0)

            // flush: 2 L1-only steps -> rows [t_hi-2, t_hi) into slots 2,3
            #pragma unroll
            for (int fs = 0; fs < 2; ++fs) {
                const float p = L ? pcc : buf[TSEG-1];   // L0 value unused
                const float P = fmaf(h0d2, sxc, p);
                const float g = fmaf(h, s_h, P);
                const float v = fmaf(Bc, fast_rcp(1.0f + exp2_(g)), Ac);
                const float w = v * qperm<0xB1>(v);
                const float cpn = fmaf(qperm<0xAA>(v), cp, qperm<0x00>(w));
                const float th = fmaf(-2.0f, fast_rcp(1.0f + exp2_(cpn)), 1.0f);
                const float hn = qperm<0xFF>(v) * th;
                if (L) { h = hn; cp = cpn;
                         if (fs == 0) hb2 = hn; else hb3 = hn; }
                h0d2 = h0d1;
            }
            if (L && gate == 0) {
                f32x4 hv = {hb0,hb1,hb2,hb3};
                st_wt_x4(so + t_hi - 4, hv);
            }

            if (s == NSEG-1 && gate == 0) {
                if (L) { st_wt(finals + 128 + bb, h);
                         st_wt(finals + 384 + bb, cp  * (0.5f/L2E)); }
                else   { st_wt(finals + bb,       h0f);
                         st_wt(finals + 256 + bb, c0f * (0.5f/L2E)); }
            }

            asm volatile("s_waitcnt vmcnt(0)" ::: "memory");  // WT payload at IC
            if (lane == 0)
                __hip_atomic_fetch_add(&flags[SCFLAG(s)], 1, __ATOMIC_RELAXED, __HIP_MEMORY_SCOPE_AGENT);
        }
        return;
    }

    // ---------------- k3 (2048 waves, chase scan) ----------------
    if (tid == 0) ready = 0;
    __syncthreads();
    const int u = (blk - NSCANB)*4 + wv;     // 0..2047: b = u>>4, quad = u&15
    const int b = u >> 4;
    for (int s = 0; s < NSEG; ++s) {
        if (tid == 0) {
            int guard = 0;
            while (__hip_atomic_load(&flags[SCFLAG(s)], __ATOMIC_RELAXED, __HIP_MEMORY_SCOPE_AGENT) < 16) {
                __builtin_amdgcn_s_sleep(2);
                if (++guard > (1<<23)) break;    // never hit legitimately
            }
            __hip_atomic_store(&ready, s+1, __ATOMIC_RELAXED, __HIP_MEMORY_SCOPE_WORKGROUP);
        }
        {
            int guard = 0;
            while (__hip_atomic_load(&ready, __ATOMIC_RELAXED, __HIP_MEMORY_SCOPE_WORKGROUP) < s+1) {
                __builtin_amdgcn_s_sleep(1);
                if (++guard > (1<<24)) break;    // never hit legitimately
            }
            asm volatile("" ::: "memory");       // no payload-load hoisting
        }
        const int t0 = s*TSEG + (u & 15)*4;
        float4 v4 = *(const float4*)(s_out + (size_t)b*SS + t0);
        #pragma unroll
        for (int jj = 0; jj < 4; ++jj) {
            const float vb = (jj==0) ? v4.x : (jj==1) ? v4.y : (jj==2) ? v4.z : v4.w;
            const f32x4 vv = {vb, vb, vb, vb};
            f32x4* dst = (f32x4*)(out + ((size_t)(t0+jj)*BB + b) * HH);
            #pragma unroll
            for (int it = 0; it < 4; ++it)
                __builtin_nontemporal_store(vv, dst + it*64 + lane);
        }
    }
    if (u < 512) {
        // finals rows: safe to overwrite pre region (scan fully done)
        const float v = finals[u];
        const f32x4 vv = {v, v, v, v};
        f32x4* dst = (f32x4*)(out + (size_t)(NROWS + u) * HH);
        #pragma unroll
        for (int it = 0; it < 4; ++it)
            __builtin_nontemporal_store(vv, dst + it*64 + lane);
    }
}

extern "C" void kernel_launch(void* const* d_in, const int* in_sizes, int n_in,
                              void* d_out, int out_size, void* d_ws, size_t ws_size,
                              hipStream_t stream) {
    const float* x    = (const float*)d_in[0];   // [S,B,H]
    const float* W    = (const float*)d_in[1];   // [L,4,D]
    const float* bias = (const float*)d_in[2];   // [L,4]
    float* out = (float*)d_out;

    float* s_out  = (float*)d_ws;                // [131072] ([b][t])
    float* finals = s_out + NROWS;               // [512]
    float* sums   = finals + 512;                // [16]
    int*   flags  = (int*)(sums + 16);           // [4608] ints

    hipMemsetAsync(flags, 0, FLAG_INTS * sizeof(int), stream);
    hipLaunchKernelGGL(k1_all, dim3(2048), dim3(256), 0, stream,
                       x, W, bias, out, sums);
    hipLaunchKernelGGL(scan_k3, dim3(NBLKB), dim3(256), 0, stream,
                       bias, out, s_out, finals, sums, flags);
}

// Round 11
// 236.825 us; speedup vs baseline: 1.0666x; 1.0666x over previous
//
#include <hip/hip_runtime.h>

#define SS 1024
#define BB 128
#define HH 1024
#define LL 2
#define DD 2048
#define NROWS (SS*BB)            // 131072 (t,b) rows
#define TSEG 512                 // D=4 dispatches
#define NSEG 2
#define ROWSEG (TSEG*BB)         // 65536 rows per segment
#define RPW 8                    // rows per wave (ROWSEG / 8192)
#define NSCANB 16                // scanner blocks (1 wave, 8 batches each)
#define NWORKB 2048              // worker blocks (4 waves each -> 8192 waves)
#define L2E  1.4426950408889634f

typedef float f32x4 __attribute__((ext_vector_type(4)));

__device__ __forceinline__ float fast_rcp(float x)  { return __builtin_amdgcn_rcpf(x); }
__device__ __forceinline__ float exp2_(float x)     { return __builtin_amdgcn_exp2f(x); }

template<int CTRL>
__device__ __forceinline__ float qperm(float x){
    return __int_as_float(__builtin_amdgcn_update_dpp(0, __float_as_int(x), CTRL, 0xF, 0xF, true));
}
__device__ __forceinline__ float rowshr4(float x){
    return __int_as_float(__builtin_amdgcn_update_dpp(0, __float_as_int(x), 0x114, 0xF, 0xF, true));
}

// R22 = R20 + s_setprio(3) on the scan wave (T5). R20's fit shows p1/p2 run
// ~63us for 256MB: the scan's serial chain co-resident with ~28 worker
// waves/CU runs ~295cy/step (issue-slot contention inflates the dependent
// chain ~2-3x vs its intrinsic ~110-150cy). Raising the ONE latency-critical
// wave's priority lets its chain ops issue promptly; 1 wave cannot starve 28
// memory-bound workers. R21's 2-dispatch split is dead: 2048-wave k3 only
// reaches ~4TB/s writes (needs 8192 waves).
//   p0: k1(seg0)                    256 MB R
//   p1: k1(seg1) || scan(seg0)      256 MB R, scan hidden if <41us
//   p2: k3(seg0) || scan(seg1)      256 MB W, scan hidden
//   p3: k3(seg1) + finals           258 MB W
__global__ __launch_bounds__(256) void fused_phase(
    const float* __restrict__ x, const float* __restrict__ W,
    const float* __restrict__ bias, float* out,
    float* __restrict__ s_out, float* __restrict__ finals,
    float* __restrict__ sums, float* __restrict__ state,
    int s1, int s2, int s3, int fin)
{
    float* pre = out + (size_t)NROWS * HH;   // hT/cT rows (2 MB) as pre scratch;
                                             // overwritten only by phase-3 finals
    const int tid = threadIdx.x;

    if (blockIdx.x < NSCANB) {
        if (tid >= 64) return;
        const int lane = tid;

        if (s2 < 0) {
            // phase 0: compute 12 weight sums once (block 0 only)
            if (blockIdx.x == 0 && s1 == 0) {
                for (int s = 0; s < 12; ++s) {
                    const int base = (s < 4) ? s*DD
                                   : (s < 8) ? 4*DD + (s-4)*DD
                                             : 4*DD + (s-8)*DD + HH;
                    float v = 0.f;
                    #pragma unroll
                    for (int k = 0; k < 16; ++k) v += W[base + lane + k*64];
                    #pragma unroll
                    for (int off = 32; off >= 1; off >>= 1) v += __shfl_xor(v, off, 64);
                    if (lane == 0) sums[s] = v;
                }
            }
            return;
        }

        // ---------------- scan segment s2 ----------------
        const int gate = lane & 3;
        const int L    = (lane >> 2) & 1;
        const int lb   = lane >> 3;
        const int bb   = blockIdx.x * 8 + lb;

        const float sh = sums[L*4 + gate];       // sum W[L][g][0:H]
        const float sx = sums[8 + gate];         // sum W[1][g][H:2H]
        const float sc  = (gate == 1) ? (2.0f*L2E) : (-L2E);
        const float s_h = sh * sc;
        const float sxc = L ? sx * sc : 0.0f;
        const float pcc = L ? bias[4+gate] * sc : 0.0f;
        const float Ac  = (gate == 1) ? 1.0f : 0.0f;
        const float Bc  = (gate == 0) ? (2.0f*L2E) : ((gate == 1) ? -2.0f : 1.0f);

        const float* pbase = pre + ((size_t)bb << 12) + gate;   // + t*4
        float* so = s_out + (size_t)bb * SS;                    // + t  (transposed)

        const int t_lo = s2 * TSEG, t_hi = t_lo + TSEG;

        float h, cp, h0d1, h0d2;                 // cp = 2*L2E*c
        float4* st = (float4*)state + blockIdx.x*64 + lane;
        if (t_lo == 0) { h = 0.f; cp = 0.f; h0d1 = 0.f; h0d2 = 0.f; }
        else { float4 s = *st; h = s.x; cp = s.y; h0d1 = s.z; h0d2 = s.w; }

        float hb0 = 0.f, hb1 = 0.f, hb2 = 0.f, hb3 = 0.f;  // h batch (slot = t&3)

        __builtin_amdgcn_s_setprio(3);   // T5: latency-critical serial chain;
                                         // outprioritize co-resident workers

        float buf[64];
        for (int ch = 0; ch < TSEG/64; ++ch) {
            const int tc = t_lo + ch*64;
            // chunk load: 64 scalars, one compiler wait before first use
            #pragma unroll
            for (int uu = 0; uu < 64; ++uu)
                buf[uu] = pbase[(size_t)(tc + uu) * 4];
            // 64 pure-VALU steps
            #pragma unroll
            for (int uu = 0; uu < 64; ++uu) {
                const float p = L ? pcc : buf[uu];
                const float P = fmaf(h0d2, sxc, p);      // L1 consumes h0_{t-2}
                const float g = fmaf(h, s_h, P);
                const float v = fmaf(Bc, fast_rcp(1.0f + exp2_(g)), Ac);
                const float w = v * qperm<0xB1>(v);
                const float cpn = fmaf(qperm<0xAA>(v), cp, qperm<0x00>(w));
                const float th = fmaf(-2.0f, fast_rcp(1.0f + exp2_(cpn)), 1.0f);
                const float hn = qperm<0xFF>(v) * th;
                // first 2 steps of segment: L1 redoes steps done by previous
                // segment's flush (or spin-up at t=0) -> discard.
                const bool disc = (ch == 0) && (uu < 2) && L;
                h  = disc ? h  : hn;
                cp = disc ? cp : cpn;
                h0d2 = h0d1;
                h0d1 = rowshr4(h);                       // L0 h -> L1 quad (DPP)

                // L1's h at global-u is h1[t_lo+u-2]; slot = (uu+2)&3
                if (((uu+2)&3)==0) hb0 = h;
                else if (((uu+2)&3)==1) hb1 = h;
                else if (((uu+2)&3)==2) hb2 = h;
                else hb3 = h;
                // store 4 rows once slot 3 filled (u%4==1, skip warm-up)
                if (((uu&3)==1) && (ch > 0 || uu >= 5) && L && gate == 0) {
                    *(float4*)(so + tc + uu - 5) = make_float4(hb0,hb1,hb2,hb3);
                }
            }
        }

        const float h0f = h, c0f = cp;           // L0 finals (flush skips L0)

        // flush: 2 L1-only steps -> rows [t_hi-2, t_hi) into slots 2,3
        #pragma unroll
        for (int fs = 0; fs < 2; ++fs) {
            const float p = L ? pcc : buf[63];   // L0 value unused this phase
            const float P = fmaf(h0d2, sxc, p);
            const float g = fmaf(h, s_h, P);
            const float v = fmaf(Bc, fast_rcp(1.0f + exp2_(g)), Ac);
            const float w = v * qperm<0xB1>(v);
            const float cpn = fmaf(qperm<0xAA>(v), cp, qperm<0x00>(w));
            const float th = fmaf(-2.0f, fast_rcp(1.0f + exp2_(cpn)), 1.0f);
            const float hn = qperm<0xFF>(v) * th;
            if (L) { h = hn; cp = cpn;
                     if (fs == 0) hb2 = hn; else hb3 = hn; }
            h0d2 = h0d1;
        }
        if (L && gate == 0)
            *(float4*)(so + t_hi - 4) = make_float4(hb0,hb1,hb2,hb3);

        __builtin_amdgcn_s_setprio(0);

        *st = make_float4(h, cp, h0d1, h0d2);    // state for next segment

        if (t_hi == SS && gate == 0) {
            if (L) { finals[128+bb] = h;   finals[384+bb] = cp  * (0.5f/L2E); }
            else   { finals[bb]     = h0f; finals[256+bb] = c0f * (0.5f/L2E); }
        }
        return;
    }

    // ---------------- BW worker ----------------
    const int lane = tid & 63;
    const int gw   = (blockIdx.x - NSCANB)*4 + (tid >> 6);   // 0..8191

    if (s1 >= 0) {
        // k1: RPW consecutive rows per wave of segment s1 -> transposed pre.
        // x is read exactly once -> nontemporal (skip L2 allocate).
        float4 wv[4][4];
        #pragma unroll
        for (int j = 0; j < 4; ++j)
            #pragma unroll
            for (int it = 0; it < 4; ++it)
                wv[j][it] = *(const float4*)(W + j*DD + HH + it*256 + lane*4);
        const float4 b0 = *(const float4*)(bias);

        #pragma unroll 2
        for (int j = 0; j < RPW; ++j) {
            const int row = s1*ROWSEG + gw*RPW + j;
            const float* xr = x + (size_t)row * HH;
            float a0 = 0.f, a1 = 0.f, a2 = 0.f, a3 = 0.f;
            #pragma unroll
            for (int it = 0; it < 4; ++it) {
                f32x4 xv = __builtin_nontemporal_load((const f32x4*)xr + it*64 + lane);
                a0 = fmaf(xv.x, wv[0][it].x, fmaf(xv.y, wv[0][it].y, fmaf(xv.z, wv[0][it].z, fmaf(xv.w, wv[0][it].w, a0))));
                a1 = fmaf(xv.x, wv[1][it].x, fmaf(xv.y, wv[1][it].y, fmaf(xv.z, wv[1][it].z, fmaf(xv.w, wv[1][it].w, a1))));
                a2 = fmaf(xv.x, wv[2][it].x, fmaf(xv.y, wv[2][it].y, fmaf(xv.z, wv[2][it].z, fmaf(xv.w, wv[2][it].w, a2))));
                a3 = fmaf(xv.x, wv[3][it].x, fmaf(xv.y, wv[3][it].y, fmaf(xv.z, wv[3][it].z, fmaf(xv.w, wv[3][it].w, a3))));
            }
            #pragma unroll
            for (int off = 32; off >= 1; off >>= 1) {
                a0 += __shfl_xor(a0, off, 64);
                a1 += __shfl_xor(a1, off, 64);
                a2 += __shfl_xor(a2, off, 64);
                a3 += __shfl_xor(a3, off, 64);
            }
            if (lane == 0) {
                float4 r = make_float4((a0 + b0.x) * (-L2E),
                                       (a1 + b0.y) * ( 2.0f * L2E),
                                       (a2 + b0.z) * (-L2E),
                                       (a3 + b0.w) * (-L2E));
                const int b = row & (BB-1), t = row >> 7;
                *(float4*)(pre + (((size_t)b << 10) + t) * 4) = r;
            }
        }
    }

    if (s3 >= 0) {
        // k3: 2 groups per wave; group = 4 consecutive t of one b (matches
        // transposed s_out[b][t] -> one broadcast float4 load per group).
        #pragma unroll
        for (int rep = 0; rep < 2; ++rep) {
            const int g  = gw*2 + rep;           // 0..16383
            const int b  = g >> 7;               // 0..127
            const int t0 = s3*TSEG + (g & 127)*4;
            float4 v4 = *(const float4*)(s_out + (size_t)b*SS + t0);
            #pragma unroll
            for (int jj = 0; jj < 4; ++jj) {
                const float vb = (jj==0) ? v4.x : (jj==1) ? v4.y : (jj==2) ? v4.z : v4.w;
                const f32x4 vv = {vb, vb, vb, vb};
                f32x4* dst = (f32x4*)(out + ((size_t)(t0+jj)*BB + b) * HH);
                #pragma unroll
                for (int it = 0; it < 4; ++it)
                    __builtin_nontemporal_store(vv, dst + it*64 + lane);
            }
        }
    }

    if (fin && gw < 512) {
        // finals: hT/cT rows (overwrites the pre region; scan is done)
        const float v = finals[gw];
        const f32x4 vv = {v, v, v, v};
        f32x4* dst = (f32x4*)(out + (size_t)(NROWS + gw) * HH);
        #pragma unroll
        for (int it = 0; it < 4; ++it)
            __builtin_nontemporal_store(vv, dst + it*64 + lane);
    }
}

extern "C" void kernel_launch(void* const* d_in, const int* in_sizes, int n_in,
                              void* d_out, int out_size, void* d_ws, size_t ws_size,
                              hipStream_t stream) {
    const float* x    = (const float*)d_in[0];   // [S,B,H]
    const float* W    = (const float*)d_in[1];   // [L,4,D]
    const float* bias = (const float*)d_in[2];   // [L,4]
    float* out = (float*)d_out;

    float* s_out  = (float*)d_ws;                // [131072] (transposed [b][t])
    float* finals = s_out + NROWS;               // [512]
    float* sums   = finals + 512;                // [16]
    float* state  = sums + 16;                   // [16*64*4] floats (16B aligned)

    // 4-phase pipeline: p0 k1(0); p1 k1(1)||scan(0); p2 k3(0)||scan(1);
    // p3 k3(1)+finals
    for (int p = 0; p < 4; ++p) {
        const int a1 = (p <= 1) ? p : -1;
        const int a2 = (p >= 1 && p <= 2) ? p - 1 : -1;
        const int a3 = (p >= 2) ? p - 2 : -1;
        const int fn = (p == 3) ? 1 : 0;
        hipLaunchKernelGGL(fused_phase, dim3(NSCANB + NWORKB), dim3(256), 0, stream,
                           x, W, bias, out, s_out, finals, sums, state,
                           a1, a2, a3, fn);
    }
}